// Round 1
// baseline (917.629 us; speedup 1.0000x reference)
//
#include <hip/hip_runtime.h>

#define NCH   96
#define RF    25
#define HALF  12
#define HW    55
#define PLANE (HW * HW)   // 3025
#define CAP   32          // max compact taps per channel; dense fallback beyond

// d_ws layout:
//   int   counts[NCH]            @ 0                          (384 B)
//   int   tap_off[NCH][CAP]      @ 384                        (12288 B)  packed (dy<<8)|dx
//   float tap_w [NCH][CAP]       @ 384 + 12288 = 12672        (12288 B)
//   total 24960 B
#define WS_NEEDED (NCH * 4 + NCH * CAP * 4 * 2)

__global__ void prep_taps(const float* __restrict__ kern, int* __restrict__ counts,
                          int* __restrict__ tap_off, float* __restrict__ tap_w) {
    int c = blockIdx.x * blockDim.x + threadIdx.x;
    if (c >= NCH) return;
    const float* kc = kern + c * (RF * RF);
    int cnt = 0;
    for (int i = 0; i < RF * RF; ++i) {
        float w = kc[i];
        if (w != 0.0f) {
            if (cnt < CAP) {
                int dy = i / RF, dx = i - dy * RF;
                tap_off[c * CAP + cnt] = (dy << 8) | dx;
                tap_w[c * CAP + cnt]   = w;
            }
            ++cnt;
        }
    }
    counts[c] = cnt;
}

// Block = 256 threads = 4 waves. Wave w handles 64 consecutive pixels (lane = pixel)
// for channel-groups c4 = w, w+4, ..., w+20 (6 iterations -> all 24 float4 groups).
// Tap count is wave-uniform (same channel across all lanes) -> no lockstep waste.
__global__ __launch_bounds__(256) void contour_fused(
        const float* __restrict__ x, const float* __restrict__ kern,
        const int* __restrict__ counts, const int* __restrict__ tap_off,
        const float* __restrict__ tap_w, float* __restrict__ out, int npix_total) {
    const int lane = threadIdx.x & 63;
    const int wave = threadIdx.x >> 6;
    const int p = blockIdx.x * 64 + lane;   // global pixel index: n*3025 + py*55 + px
    if (p >= npix_total) return;
    const int n  = p / PLANE;
    const int r  = p - n * PLANE;
    const int py = r / HW;
    const int px = r - py * HW;
    const float* xn = x + (size_t)n * (PLANE * NCH);
    const size_t pbase = (size_t)p * NCH;

    #pragma unroll
    for (int i = 0; i < 6; ++i) {
        const int c4 = wave + 4 * i;        // 0..23
        const float4 xv = *reinterpret_cast<const float4*>(x + pbase + c4 * 4);
        float acc[4] = {xv.x, xv.y, xv.z, xv.w};
        #pragma unroll
        for (int kk = 0; kk < 4; ++kk) {
            const int c = c4 * 4 + kk;
            const int cnt = counts ? counts[c] : (CAP + 1);
            if (cnt == 0) continue;
            float a = 0.0f;
            if (cnt <= CAP) {
                for (int t = 0; t < cnt; ++t) {
                    const int off = tap_off[c * CAP + t];
                    const float w = tap_w[c * CAP + t];
                    const int dy = off >> 8, dx = off & 255;
                    const int yy = py + dy - HALF;
                    const int xx = px + dx - HALF;
                    if ((unsigned)yy < (unsigned)HW && (unsigned)xx < (unsigned)HW)
                        a += w * xn[(size_t)(yy * HW + xx) * NCH + c];
                }
            } else {
                // generic dense fallback (never taken for the reference mask)
                for (int dy = 0; dy < RF; ++dy) {
                    for (int dx = 0; dx < RF; ++dx) {
                        const float w = kern[(c * RF + dy) * RF + dx];
                        if (w == 0.0f) continue;
                        const int yy = py + dy - HALF;
                        const int xx = px + dx - HALF;
                        if ((unsigned)yy < (unsigned)HW && (unsigned)xx < (unsigned)HW)
                            a += w * xn[(size_t)(yy * HW + xx) * NCH + c];
                    }
                }
            }
            acc[kk] += a;
        }
        *reinterpret_cast<float4*>(out + pbase + c4 * 4) =
            make_float4(acc[0], acc[1], acc[2], acc[3]);
    }
}

extern "C" void kernel_launch(void* const* d_in, const int* in_sizes, int n_in,
                              void* d_out, int out_size, void* d_ws, size_t ws_size,
                              hipStream_t stream) {
    const float* x    = (const float*)d_in[0];
    const float* kern = (const float*)d_in[1];
    float* out = (float*)d_out;

    const int total = in_sizes[0];        // 128*55*55*96 = 37,171,200
    const int npix  = total / NCH;        // 387,200

    int*   counts  = nullptr;
    int*   tap_off = nullptr;
    float* tap_w   = nullptr;
    if (ws_size >= (size_t)WS_NEEDED) {
        counts  = (int*)d_ws;
        tap_off = (int*)((char*)d_ws + NCH * 4);
        tap_w   = (float*)((char*)d_ws + NCH * 4 + NCH * CAP * 4);
        prep_taps<<<1, 128, 0, stream>>>(kern, counts, tap_off, tap_w);
    }

    const int nblocks = (npix + 63) / 64; // 6050
    contour_fused<<<nblocks, 256, 0, stream>>>(x, kern, counts, tap_off, tap_w, out, npix);
}

// Round 2
// 654.986 us; speedup vs baseline: 1.4010x; 1.4010x over previous
//
#include <hip/hip_runtime.h>

#define NCH   96
#define RF    25
#define HALF  12
#define HW    55
#define PLANE (HW * HW)   // 3025
#define CAP   32          // max compact taps per channel; dense fallback beyond
#define MAXA  6           // max active channels on the LDS fast path
#define TH    5           // output rows per block (55 = 11*5 exact)
#define SROWS (TH + 2*HALF)  // 29 staged rows
#define LDSW  56          // padded row width in LDS

// d_ws layout:
//   int   counts[NCH]            @ 0        (384 B)
//   int   tap_off[NCH][CAP]      @ 384      (12288 B)  packed (dy<<8)|dx
//   float tap_w [NCH][CAP]       @ 12672    (12288 B)
//   int   meta[1+MAXA]           @ 24960    (n_active, active_ch[]; 999 if dense needed)
#define WS_META_OFF (NCH * 4 + NCH * CAP * 4 * 2)
#define WS_NEEDED (WS_META_OFF + (1 + MAXA) * 4)

__global__ void prep_taps(const float* __restrict__ kern, int* __restrict__ counts,
                          int* __restrict__ tap_off, float* __restrict__ tap_w,
                          int* __restrict__ meta) {
    int c = threadIdx.x;
    if (c < NCH) {
        const float* kc = kern + c * (RF * RF);
        int cnt = 0;
        for (int i = 0; i < RF * RF; ++i) {
            float w = kc[i];
            if (w != 0.0f) {
                if (cnt < CAP) {
                    int dy = i / RF, dx = i - dy * RF;
                    tap_off[c * CAP + cnt] = (dy << 8) | dx;
                    tap_w[c * CAP + cnt]   = w;
                }
                ++cnt;
            }
        }
        counts[c] = cnt;
    }
    __syncthreads();
    if (threadIdx.x == 0) {
        int na = 0;
        bool dense = false;
        for (int ch = 0; ch < NCH; ++ch) {
            if (counts[ch] > 0) {
                if (counts[ch] > CAP) dense = true;
                if (na < MAXA) meta[1 + na] = ch;
                ++na;
            }
        }
        meta[0] = (dense || na > MAXA) ? 999 : na;
        for (int a = na; a < MAXA; ++a) meta[1 + a] = 0;
    }
}

// Block = 256 threads = 1 image-stripe (TH rows x 55 cols x 96 ch).
// Grid = 8 XCD-slots x 176: all 11 stripes of image n land on XCD n%8, back-to-back.
__global__ __launch_bounds__(256, 4) void contour_tile(
        const float* __restrict__ x,
        const int* __restrict__ counts, const int* __restrict__ tap_off,
        const float* __restrict__ tap_w, const int* __restrict__ meta,
        float* __restrict__ out) {
    __shared__ float sh[MAXA][SROWS][LDSW];

    const int b    = blockIdx.x;
    const int xcd  = b & 7;
    const int slot = b >> 3;          // 0..175
    const int imgI = slot / 11;       // 0..15
    const int ty   = slot - imgI * 11;
    const int n    = xcd + (imgI << 3);
    const int y0   = ty * TH;

    const float* xn = x   + (size_t)n * (PLANE * NCH);
    float*       on = out + (size_t)n * (PLANE * NCH);

    const int n_active = meta[0];

    if (n_active <= MAXA) {
        // ---- phase 1: stage active-channel halo window into LDS ----
        const int tot = n_active * (SROWS * HW);
        for (int idx = threadIdx.x; idx < tot; idx += 256) {
            const int a   = idx / (SROWS * HW);
            const int rem = idx - a * (SROWS * HW);
            const int s   = rem / HW;
            const int col = rem - s * HW;
            const int gy  = y0 - HALF + s;
            float v = 0.0f;
            if ((unsigned)gy < (unsigned)HW)
                v = xn[(size_t)(gy * HW + col) * NCH + meta[1 + a]];
            sh[a][s][col] = v;
        }
        __syncthreads();

        // ---- phase 2: coalesced stripe copy out = x (all channels) ----
        const float4* xs = (const float4*)(xn + (size_t)y0 * HW * NCH);
        float4*       os = (float4*)      (on + (size_t)y0 * HW * NCH);
        const int totc = TH * HW * (NCH / 4);   // 6600
        for (int idx = threadIdx.x; idx < totc; idx += 256)
            os[idx] = xs[idx];
        __syncthreads();   // order phase-2 stores before phase-3 overwrites

        // ---- phase 3: lateral for active channels, overwrite out ----
        const int totb = n_active * (TH * HW);
        for (int idx = threadIdx.x; idx < totb; idx += 256) {
            const int a   = idx / (TH * HW);
            const int rem = idx - a * (TH * HW);
            const int r   = rem / HW;
            const int col = rem - r * HW;
            const int c   = meta[1 + a];
            const int cnt = counts[c];
            float acc = sh[a][r + HALF][col];   // the residual x value
            for (int t = 0; t < cnt; ++t) {
                const int off = tap_off[c * CAP + t];
                const float w = tap_w[c * CAP + t];
                const int dy = off >> 8, dx = off & 255;
                const int xx = col + dx - HALF;
                const bool ok = (unsigned)xx < (unsigned)HW;
                const int  xc = min(max(xx, 0), HW - 1);
                const float v = sh[a][r + dy][xc];
                acc += ok ? w * v : 0.0f;
            }
            on[(size_t)((y0 + r) * HW + col) * NCH + c] = acc;
        }
    } else {
        // ---- generic fallback: per-pixel compact/dense gather (never taken
        // for the reference mask) ----
        const int py0 = y0;
        for (int idx = threadIdx.x; idx < TH * HW * (NCH / 4); idx += 256) {
            const int g   = idx % (NCH / 4);
            const int pix = idx / (NCH / 4);
            const int r   = pix / HW;
            const int col = pix - r * HW;
            const int py  = py0 + r;
            const size_t pbase = (size_t)(py * HW + col) * NCH;
            const float4 xv = *(const float4*)(xn + pbase + g * 4);
            float acc[4] = {xv.x, xv.y, xv.z, xv.w};
            for (int kk = 0; kk < 4; ++kk) {
                const int c = g * 4 + kk;
                const int cnt = counts[c];
                if (cnt == 0) continue;
                float a = 0.0f;
                if (cnt <= CAP) {
                    for (int t = 0; t < cnt; ++t) {
                        const int off = tap_off[c * CAP + t];
                        const float w = tap_w[c * CAP + t];
                        const int dy = off >> 8, dx = off & 255;
                        const int yy = py + dy - HALF;
                        const int xx = col + dx - HALF;
                        if ((unsigned)yy < (unsigned)HW && (unsigned)xx < (unsigned)HW)
                            a += w * xn[(size_t)(yy * HW + xx) * NCH + c];
                    }
                }
                acc[kk] += a;
            }
            *(float4*)(on + pbase + g * 4) = make_float4(acc[0], acc[1], acc[2], acc[3]);
        }
    }
}

extern "C" void kernel_launch(void* const* d_in, const int* in_sizes, int n_in,
                              void* d_out, int out_size, void* d_ws, size_t ws_size,
                              hipStream_t stream) {
    const float* x    = (const float*)d_in[0];
    const float* kern = (const float*)d_in[1];
    float* out = (float*)d_out;

    int*   counts  = (int*)d_ws;
    int*   tap_off = (int*)((char*)d_ws + NCH * 4);
    float* tap_w   = (float*)((char*)d_ws + NCH * 4 + NCH * CAP * 4);
    int*   meta    = (int*)((char*)d_ws + WS_META_OFF);

    prep_taps<<<1, 128, 0, stream>>>(kern, counts, tap_off, tap_w, meta);

    // 128 images x 11 stripes, XCD-swizzled
    contour_tile<<<8 * 176, 256, 0, stream>>>(x, counts, tap_off, tap_w, meta, out);
}

// Round 3
// 417.235 us; speedup vs baseline: 2.1993x; 1.5698x over previous
//
#include <hip/hip_runtime.h>

#define NCH   96
#define RF    25
#define HALF  12
#define HW    55
#define PLANE (HW * HW)   // 3025
#define CAP   32          // max compact taps per channel; dense fallback beyond
#define MAXA  6           // max active channels on the LDS fast path
#define TH    11          // output rows per block (55 = 5*11 exact)
#define SROWS (TH + 2*HALF)  // 35 staged rows
#define LDSW  56          // padded row width in LDS

// d_ws layout:
//   int   counts[NCH]            @ 0        (384 B)
//   int   tap_off[NCH][CAP]      @ 384      (12288 B)  packed (dy<<8)|dx
//   float tap_w [NCH][CAP]       @ 12672    (12288 B)
//   int   meta[1+MAXA]           @ 24960    (n_active, active_ch[]; 999 if fallback)
#define WS_META_OFF (NCH * 4 + NCH * CAP * 4 * 2)

// One wave per channel: coalesced scan + ballot-prefix compaction.
__global__ void prep_taps(const float* __restrict__ kern, int* __restrict__ counts,
                          int* __restrict__ tap_off, float* __restrict__ tap_w) {
    const int c    = blockIdx.x;
    const int lane = threadIdx.x;           // 0..63
    const float* kc = kern + c * (RF * RF);
    int base = 0;
    for (int seg = 0; seg < RF * RF; seg += 64) {
        const int i = seg + lane;
        const float w = (i < RF * RF) ? kc[i] : 0.0f;
        const unsigned long long m = __ballot(w != 0.0f);
        const int pos = base + __popcll(m & ((1ull << lane) - 1ull));
        if (w != 0.0f && pos < CAP) {
            const int dy = i / RF, dx = i - dy * RF;
            tap_off[c * CAP + pos] = (dy << 8) | dx;
            tap_w[c * CAP + pos]   = w;
        }
        base += __popcll(m);
    }
    if (lane == 0) counts[c] = base;
}

__global__ void prep_meta(const int* __restrict__ counts, int* __restrict__ meta) {
    __shared__ int scnt[NCH];
    if (threadIdx.x < NCH) scnt[threadIdx.x] = counts[threadIdx.x];
    __syncthreads();
    if (threadIdx.x == 0) {
        int na = 0;
        bool fallback = false;
        for (int ch = 0; ch < NCH; ++ch) {
            if (scnt[ch] > 0) {
                if (scnt[ch] > CAP) fallback = true;
                if (na < MAXA) meta[1 + na] = ch;
                ++na;
            }
        }
        if (na > MAXA) fallback = true;
        meta[0] = fallback ? 999 : na;
        for (int a = (na > MAXA ? 0 : na); a < MAXA; ++a) meta[1 + a] = 0;
    }
}

// Block = 256 threads = 1 image-stripe (TH rows x 55 cols x 96 ch).
// Grid = 8 XCD-slots x 80: all 5 stripes of image n land on XCD n%8, adjacent.
__global__ __launch_bounds__(256, 3) void contour_tile(
        const float* __restrict__ x, const float* __restrict__ kern,
        const int* __restrict__ counts, const int* __restrict__ tap_off,
        const float* __restrict__ tap_w, const int* __restrict__ meta,
        float* __restrict__ out) {
    __shared__ float sh[MAXA][SROWS][LDSW];   // 47,040 B

    const int b    = blockIdx.x;
    const int xcd  = b & 7;
    const int slot = b >> 3;          // 0..79
    const int imgI = slot / 5;        // 0..15
    const int ty   = slot - imgI * 5; // 0..4
    const int n    = xcd + (imgI << 3);
    const int y0   = ty * TH;

    const float* xn = x   + (size_t)n * (PLANE * NCH);
    float*       on = out + (size_t)n * (PLANE * NCH);

    const int n_active = meta[0];

    if (n_active <= MAXA) {
        // ---- phase 1: stage active-channel halo window into LDS ----
        const int tot = n_active * (SROWS * HW);
        for (int idx = threadIdx.x; idx < tot; idx += 256) {
            const int a   = idx / (SROWS * HW);
            const int rem = idx - a * (SROWS * HW);
            const int s   = rem / HW;
            const int col = rem - s * HW;
            const int gy  = y0 - HALF + s;
            float v = 0.0f;
            if ((unsigned)gy < (unsigned)HW)
                v = xn[(size_t)(gy * HW + col) * NCH + meta[1 + a]];
            sh[a][s][col] = v;
        }
        __syncthreads();

        // ---- phase 2: coalesced stripe copy out = x (all channels) ----
        const float4* xs = (const float4*)(xn + (size_t)y0 * HW * NCH);
        float4*       os = (float4*)      (on + (size_t)y0 * HW * NCH);
        const int totc = TH * HW * (NCH / 4);   // 14,520
        for (int idx = threadIdx.x; idx < totc; idx += 256)
            os[idx] = xs[idx];
        __syncthreads();   // order phase-2 stores before phase-3 overwrites

        // ---- phase 3: lateral for active channels, overwrite out ----
        const int totb = n_active * (TH * HW);
        for (int idx = threadIdx.x; idx < totb; idx += 256) {
            const int a   = idx / (TH * HW);
            const int rem = idx - a * (TH * HW);
            const int r   = rem / HW;
            const int col = rem - r * HW;
            const int c   = meta[1 + a];
            const int cnt = counts[c];
            float acc = sh[a][r + HALF][col];   // the residual x value
            for (int t = 0; t < cnt; ++t) {
                const int off = tap_off[c * CAP + t];
                const float w = tap_w[c * CAP + t];
                const int dy = off >> 8, dx = off & 255;
                const int xx = col + dx - HALF;
                const bool ok = (unsigned)xx < (unsigned)HW;
                const int  xc = min(max(xx, 0), HW - 1);
                const float v = sh[a][r + dy][xc];
                acc += ok ? w * v : 0.0f;
            }
            on[(size_t)((y0 + r) * HW + col) * NCH + c] = acc;
        }
    } else {
        // ---- generic fallback: per-pixel gather (never taken for the
        // reference mask) ----
        for (int idx = threadIdx.x; idx < TH * HW * (NCH / 4); idx += 256) {
            const int g   = idx % (NCH / 4);
            const int pix = idx / (NCH / 4);
            const int r   = pix / HW;
            const int col = pix - r * HW;
            const int py  = y0 + r;
            const size_t pbase = (size_t)(py * HW + col) * NCH;
            const float4 xv = *(const float4*)(xn + pbase + g * 4);
            float acc[4] = {xv.x, xv.y, xv.z, xv.w};
            for (int kk = 0; kk < 4; ++kk) {
                const int c = g * 4 + kk;
                const int cnt = counts[c];
                if (cnt == 0) continue;
                float a = 0.0f;
                if (cnt <= CAP) {
                    for (int t = 0; t < cnt; ++t) {
                        const int off = tap_off[c * CAP + t];
                        const float w = tap_w[c * CAP + t];
                        const int dy = off >> 8, dx = off & 255;
                        const int yy = py + dy - HALF;
                        const int xx = col + dx - HALF;
                        if ((unsigned)yy < (unsigned)HW && (unsigned)xx < (unsigned)HW)
                            a += w * xn[(size_t)(yy * HW + xx) * NCH + c];
                    }
                } else {
                    for (int dy = 0; dy < RF; ++dy) {
                        for (int dx = 0; dx < RF; ++dx) {
                            const float w = kern[(c * RF + dy) * RF + dx];
                            if (w == 0.0f) continue;
                            const int yy = py + dy - HALF;
                            const int xx = col + dx - HALF;
                            if ((unsigned)yy < (unsigned)HW && (unsigned)xx < (unsigned)HW)
                                a += w * xn[(size_t)(yy * HW + xx) * NCH + c];
                        }
                    }
                }
                acc[kk] += a;
            }
            *(float4*)(on + pbase + g * 4) = make_float4(acc[0], acc[1], acc[2], acc[3]);
        }
    }
}

extern "C" void kernel_launch(void* const* d_in, const int* in_sizes, int n_in,
                              void* d_out, int out_size, void* d_ws, size_t ws_size,
                              hipStream_t stream) {
    const float* x    = (const float*)d_in[0];
    const float* kern = (const float*)d_in[1];
    float* out = (float*)d_out;

    int*   counts  = (int*)d_ws;
    int*   tap_off = (int*)((char*)d_ws + NCH * 4);
    float* tap_w   = (float*)((char*)d_ws + NCH * 4 + NCH * CAP * 4);
    int*   meta    = (int*)((char*)d_ws + WS_META_OFF);

    prep_taps<<<NCH, 64, 0, stream>>>(kern, counts, tap_off, tap_w);
    prep_meta<<<1, 128, 0, stream>>>(counts, meta);

    // 128 images x 5 stripes, XCD-swizzled
    contour_tile<<<8 * 80, 256, 0, stream>>>(x, kern, counts, tap_off, tap_w, meta, out);
}

// Round 4
// 382.172 us; speedup vs baseline: 2.4011x; 1.0917x over previous
//
#include <hip/hip_runtime.h>

#define NCH   96
#define RF    25
#define HALF  12
#define HW    55
#define PLANE (HW * HW)   // 3025
#define CAP   32          // max compact taps per channel; dense fallback beyond
#define MAXA  6           // max active channels on the LDS fast path
#define SROWS 38          // 14 output rows + 24 halo
#define LDSW  56          // padded row width in LDS

// d_ws layout:
//   int   counts[NCH]            @ 0        (384 B)
//   int   tap_off[NCH][CAP]      @ 384      (12288 B)  packed (dy<<8)|dx
//   float tap_w [NCH][CAP]       @ 12672    (12288 B)
//   int   meta[1+MAXA]           @ 24960    (n_active, active_ch[]; 999 if fallback)
#define WS_META_OFF (NCH * 4 + NCH * CAP * 4 * 2)

// Single prep launch: 16 waves scan 6 channels each (ballot-compaction),
// then thread 0 builds the active-channel meta list.
__global__ __launch_bounds__(1024) void prep_all(
        const float* __restrict__ kern, int* __restrict__ counts,
        int* __restrict__ tap_off, float* __restrict__ tap_w,
        int* __restrict__ meta) {
    __shared__ int scnt[NCH];
    const int wave = threadIdx.x >> 6;
    const int lane = threadIdx.x & 63;
    for (int c = wave; c < NCH; c += 16) {
        const float* kc = kern + c * (RF * RF);
        int base = 0;
        for (int seg = 0; seg < RF * RF; seg += 64) {
            const int i = seg + lane;
            const float w = (i < RF * RF) ? kc[i] : 0.0f;
            const unsigned long long m = __ballot(w != 0.0f);
            const int pos = base + __popcll(m & ((1ull << lane) - 1ull));
            if (w != 0.0f && pos < CAP) {
                const int dy = i / RF, dx = i - dy * RF;
                tap_off[c * CAP + pos] = (dy << 8) | dx;
                tap_w[c * CAP + pos]   = w;
            }
            base += __popcll(m);
        }
        if (lane == 0) { counts[c] = base; scnt[c] = base; }
    }
    __syncthreads();
    if (threadIdx.x == 0) {
        int na = 0;
        bool fallback = false;
        for (int ch = 0; ch < NCH; ++ch) {
            if (scnt[ch] > 0) {
                if (scnt[ch] > CAP) fallback = true;
                if (na < MAXA) meta[1 + na] = ch;
                ++na;
            }
        }
        if (na > MAXA) fallback = true;
        meta[0] = fallback ? 999 : na;
        for (int a = (na > MAXA ? 0 : na); a < MAXA; ++a) meta[1 + a] = 0;
    }
}

// Block = quarter-image (rows q*14 .. q*14+13, last block 13 rows), 1024 thr.
// Grid = 512, swizzled: the 4 sibling blocks of image n land on XCD n%8,
// adjacent in dispatch order -> halo lines L2-shared with tight timing.
__global__ __launch_bounds__(1024, 8) void contour_tile(
        const float* __restrict__ x, const float* __restrict__ kern,
        const int* __restrict__ counts, const int* __restrict__ tap_off,
        const float* __restrict__ tap_w, const int* __restrict__ meta,
        float* __restrict__ out) {
    __shared__ float sh[MAXA][SROWS][LDSW];   // 51,072 B
    __shared__ float tw[MAXA][CAP];
    __shared__ int   toff[MAXA][CAP];
    __shared__ int   tcnt[MAXA];
    __shared__ int   chA[MAXA];
    __shared__ signed char c2a[NCH];

    const int tid  = threadIdx.x;
    const int b    = blockIdx.x;
    const int xcd  = b & 7;
    const int s    = b >> 3;          // 0..63
    const int n    = xcd + ((s >> 2) << 3);   // image 0..127
    const int q    = s & 3;           // quarter 0..3
    const int y0   = q * 14;
    const int rows = (q < 3) ? 14 : 13;
    const int npx  = rows * HW;

    const float* xn = x   + (size_t)n * (PLANE * NCH);
    float*       on = out + (size_t)n * (PLANE * NCH);

    const int na = meta[0];
    const bool fast = (na <= MAXA);

    // ---- phase 0: tap/meta tables into LDS ----
    if (tid < NCH) c2a[tid] = -1;
    __syncthreads();
    if (fast) {
        if (tid < MAXA) {
            const int c = (tid < na) ? meta[1 + tid] : -1;
            chA[tid]  = c;
            tcnt[tid] = (c >= 0) ? counts[c] : 0;
        }
        if (tid < na) c2a[meta[1 + tid]] = (signed char)tid;
        if (tid >= 64 && tid < 64 + MAXA * CAP) {
            const int a = (tid - 64) / CAP, t = (tid - 64) % CAP;
            const int c = (a < na) ? meta[1 + a] : 0;
            toff[a][t] = tap_off[c * CAP + t];
            tw[a][t]   = tap_w[c * CAP + t];
        }
    }
    __syncthreads();

    // ---- phase A: coalesced copy out = x, fused LDS extraction ----
    {
        const float4* xs = (const float4*)(xn + (size_t)y0 * HW * NCH);
        float4*       os = (float4*)      (on + (size_t)y0 * HW * NCH);
        const int totA = npx * (NCH / 4);
        for (int idx = tid; idx < totA; idx += 1024) {
            const float4 v = xs[idx];
            os[idx] = v;
            if (fast) {
                const int pixel = idx / 24;
                const int g     = idx - pixel * 24;
                const int r     = pixel / HW;
                const int col   = pixel - r * HW;
                const float vv[4] = {v.x, v.y, v.z, v.w};
                #pragma unroll
                for (int kk = 0; kk < 4; ++kk) {
                    const int a = c2a[g * 4 + kk];
                    if (a >= 0) sh[a][r + HALF][col] = vv[kk];
                }
            }
        }
    }

    if (fast) {
        // ---- phase B: halo rows (12 above + 12 below) into LDS ----
        const int totB = na * 24 * HW;
        for (int idx = tid; idx < totB; idx += 1024) {
            const int a   = idx / (24 * HW);
            const int rem = idx - a * (24 * HW);
            const int hs  = rem / HW;
            const int col = rem - hs * HW;
            const int sr  = (hs < HALF) ? hs : hs + rows;   // plane row
            const int gy  = y0 - HALF + sr;
            float v = 0.0f;
            if ((unsigned)gy < (unsigned)HW)
                v = xn[(size_t)(gy * HW + col) * NCH + chA[a]];
            sh[a][sr][col] = v;
        }
        __syncthreads();

        // ---- phase C: lateral for active channels, overwrite out ----
        const int totC = na * npx;
        for (int idx = tid; idx < totC; idx += 1024) {
            const int a   = idx / npx;
            const int rem = idx - a * npx;
            const int r   = rem / HW;
            const int col = rem - r * HW;
            const int cnt = tcnt[a];
            float acc = sh[a][r + HALF][col];   // residual x
            for (int t = 0; t < cnt; ++t) {
                const int off = toff[a][t];
                const float w = tw[a][t];
                const int dy = off >> 8, dx = off & 255;
                const int xx = col + dx - HALF;
                const bool ok = (unsigned)xx < (unsigned)HW;
                const int  xc = min(max(xx, 0), HW - 1);
                const float v = sh[a][r + dy][xc];
                acc += ok ? w * v : 0.0f;
            }
            on[(size_t)((y0 + r) * HW + col) * NCH + chA[a]] = acc;
        }
    } else {
        // ---- generic fallback (never taken for the reference mask) ----
        for (int idx = tid; idx < npx * (NCH / 4); idx += 1024) {
            const int g   = idx % (NCH / 4);
            const int pix = idx / (NCH / 4);
            const int r   = pix / HW;
            const int col = pix - r * HW;
            const int py  = y0 + r;
            const size_t pbase = (size_t)(py * HW + col) * NCH;
            const float4 xv = *(const float4*)(xn + pbase + g * 4);
            float acc[4] = {xv.x, xv.y, xv.z, xv.w};
            for (int kk = 0; kk < 4; ++kk) {
                const int c = g * 4 + kk;
                const int cnt = counts[c];
                if (cnt == 0) continue;
                float aa = 0.0f;
                if (cnt <= CAP) {
                    for (int t = 0; t < cnt; ++t) {
                        const int off = tap_off[c * CAP + t];
                        const float w = tap_w[c * CAP + t];
                        const int dy = off >> 8, dx = off & 255;
                        const int yy = py + dy - HALF;
                        const int xx = col + dx - HALF;
                        if ((unsigned)yy < (unsigned)HW && (unsigned)xx < (unsigned)HW)
                            aa += w * xn[(size_t)(yy * HW + xx) * NCH + c];
                    }
                } else {
                    for (int dy = 0; dy < RF; ++dy)
                        for (int dx = 0; dx < RF; ++dx) {
                            const float w = kern[(c * RF + dy) * RF + dx];
                            if (w == 0.0f) continue;
                            const int yy = py + dy - HALF;
                            const int xx = col + dx - HALF;
                            if ((unsigned)yy < (unsigned)HW && (unsigned)xx < (unsigned)HW)
                                aa += w * xn[(size_t)(yy * HW + xx) * NCH + c];
                        }
                }
                acc[kk] += aa;
            }
            *(float4*)(on + pbase + g * 4) = make_float4(acc[0], acc[1], acc[2], acc[3]);
        }
    }
}

extern "C" void kernel_launch(void* const* d_in, const int* in_sizes, int n_in,
                              void* d_out, int out_size, void* d_ws, size_t ws_size,
                              hipStream_t stream) {
    const float* x    = (const float*)d_in[0];
    const float* kern = (const float*)d_in[1];
    float* out = (float*)d_out;

    int*   counts  = (int*)d_ws;
    int*   tap_off = (int*)((char*)d_ws + NCH * 4);
    float* tap_w   = (float*)((char*)d_ws + NCH * 4 + NCH * CAP * 4);
    int*   meta    = (int*)((char*)d_ws + WS_META_OFF);

    prep_all<<<1, 1024, 0, stream>>>(kern, counts, tap_off, tap_w, meta);

    // 128 images x 4 quarter-stripes, XCD-swizzled (siblings share an XCD)
    contour_tile<<<512, 1024, 0, stream>>>(x, kern, counts, tap_off, tap_w, meta, out);
}